// Round 6
// baseline (2889.334 us; speedup 1.0000x reference)
//
#include <hip/hip_runtime.h>
#include <hip/hip_bf16.h>

#define LAYERS 8
#define H_ 16
#define E_ 1024
#define D_ 64
#define FF_ 4096
#define V_ 2048
#define B_ 4
#define T_ 1024
#define MTOK (B_*T_)

typedef __bf16 bf16x8_t __attribute__((ext_vector_type(8)));
typedef float f32x4_t __attribute__((ext_vector_type(4)));
typedef __hip_bfloat16 bf16_t;

__device__ __forceinline__ bf16_t f2b(float f) { return __float2bfloat16(f); }

// ---------------- embedding: x = tok_emb[tok] + pos_emb[tok] (pos indexed by TOKEN id per ref) ----
__global__ void embed_kernel(const int* __restrict__ tokens,
                             const float* __restrict__ te,
                             const float* __restrict__ pe,
                             float* __restrict__ x) {
  int row = blockIdx.x;
  int tok = tokens[row];
  const float4* a = (const float4*)(te + (size_t)tok * E_);
  const float4* p = (const float4*)(pe + (size_t)tok * E_);
  float4* o = (float4*)(x + (size_t)row * E_);
  int t = threadIdx.x;
  float4 va = a[t], vp = p[t];
  o[t] = make_float4(va.x + vp.x, va.y + vp.y, va.z + vp.z, va.w + vp.w);
}

// ---------------- layernorm: x <- ln(x); xb <- bf16(ln(x)); wave-shuffle reduction ----------------
__global__ __launch_bounds__(256) void ln_kernel(float* __restrict__ x,
                                                 bf16_t* __restrict__ xb,
                                                 const float* __restrict__ g,
                                                 const float* __restrict__ b) {
  int row = blockIdx.x, tid = threadIdx.x;
  float* xr = x + (size_t)row * E_;
  float4 v = ((const float4*)xr)[tid];
  float s  = v.x + v.y + v.z + v.w;
  float sq = v.x*v.x + v.y*v.y + v.z*v.z + v.w*v.w;
  for (int off = 32; off; off >>= 1) {
    s  += __shfl_xor(s, off, 64);
    sq += __shfl_xor(sq, off, 64);
  }
  __shared__ float2 wred[4];
  if ((tid & 63) == 0) wred[tid >> 6] = make_float2(s, sq);
  __syncthreads();
  float2 w0 = wred[0], w1 = wred[1], w2 = wred[2], w3 = wred[3];
  float S = w0.x + w1.x + w2.x + w3.x, SQ = w0.y + w1.y + w2.y + w3.y;
  float mean = S * (1.0f / E_);
  float var  = SQ * (1.0f / E_) - mean * mean;
  float inv = rsqrtf(var + 1e-5f);
  float4 gv = ((const float4*)g)[tid];
  float4 bv = ((const float4*)b)[tid];
  float o0 = (v.x - mean) * inv * gv.x + bv.x;
  float o1 = (v.y - mean) * inv * gv.y + bv.y;
  float o2 = (v.z - mean) * inv * gv.z + bv.z;
  float o3 = (v.w - mean) * inv * gv.w + bv.w;
  ((float4*)xr)[tid] = make_float4(o0, o1, o2, o3);
  bf16_t* xo = xb + (size_t)row * E_ + tid * 4;
  xo[0] = f2b(o0); xo[1] = f2b(o1); xo[2] = f2b(o2); xo[3] = f2b(o3);
}

// ---------------- batched transpose + fp32->bf16: out[z][c][r] = in[z][r][c] ----------------
__global__ void transpose_kernel(const float* __restrict__ in, bf16_t* __restrict__ out,
                                 int R, int C) {
  __shared__ float tile[32][33];
  int z = blockIdx.z;
  const float* ib = in + (size_t)z * R * C;
  bf16_t* ob = out + (size_t)z * R * C;
  int r0 = blockIdx.y * 32, c0 = blockIdx.x * 32;
  int tx = threadIdx.x, ty = threadIdx.y;   // (32,8)
  for (int i = 0; i < 4; i++)
    tile[ty + i * 8][tx] = ib[(size_t)(r0 + ty + i * 8) * C + (c0 + tx)];
  __syncthreads();
  for (int i = 0; i < 4; i++)
    ob[(size_t)(c0 + ty + i * 8) * R + (r0 + tx)] = f2b(tile[tx][ty + i * 8]);
}

enum { MODE_F32 = 0, MODE_BF16 = 1, MODE_QKV = 2 };

__device__ __forceinline__ void gload16(const bf16_t* g, bf16_t* l) {
  __builtin_amdgcn_global_load_lds((const __attribute__((address_space(1))) void*)g,
                                   (__attribute__((address_space(3))) void*)l, 16, 0, 0);
}

// bijective XCD-aware swizzle (m204): contiguous tile chunk per XCD
__device__ __forceinline__ int xcd_swz(int flat, int nwg) {
  int q = nwg >> 3, r = nwg & 7;
  int xcd = flat & 7, idx = flat >> 3;
  return (xcd < r ? xcd * (q + 1) : r * (q + 1) + (xcd - r) * q) + idx;
}

// ---------------- 256xBN MFMA GEMM, BK=64, 8 waves, counted-vmcnt pipeline (T3/T4/T5) ----------
// A: [M,K] bf16 rows stride lda; Bt: [N,K] bf16 rows stride ldb. M%256==0, N%BN==0, kspan%64==0.
// LDS layout: frag-major 1024B subtiles, sub = frag_row*2 + ks; within: (hi*16 + r)*16B.
// gload_lds: linear dest (subtile), per-lane permuted global source -> conflict-free ds_read_b128.
// grid z = split-K slice (kbase = z*kspan); partials at C + z*sCz.
template <int BN, int MODE>
__global__ __launch_bounds__(512, 2) void gemm256_kernel(
    const bf16_t* __restrict__ A, int lda,
    const bf16_t* __restrict__ Bt, int ldb,
    void* __restrict__ C, long long sCz,
    const float* __restrict__ bias,
    const float* __restrict__ resid,
    int M, int N, int kspan, int relu) {
  constexpr int WN = BN / 64;          // waves along N (4 or 2)
  constexpr int WM = 8 / WN;           // waves along M (2 or 4)
  constexpr int MF = 16 / WM;          // m-frags per wave (8 or 4)
  constexpr int ACH = 4;               // A subtiles staged per wave
  constexpr int BCH = BN / 64;         // B subtiles staged per wave
  constexpr int LPS = ACH + BCH;       // gload_lds per thread per K-tile
  __shared__ __align__(16) bf16_t As[2][256 * 64];
  __shared__ __align__(16) bf16_t Bs[2][BN * 64];
  int tid = threadIdx.x, lane = tid & 63, wave = tid >> 6;
  int wm = wave / WN, wn = wave % WN;
  int z = blockIdx.z;
  int nwg = gridDim.x * gridDim.y;
  int flat = xcd_swz(blockIdx.y * gridDim.x + blockIdx.x, nwg);
  int m0 = (flat / gridDim.x) * 256, n0 = (flat % gridDim.x) * BN;
  const bf16_t* Ab = A + (size_t)m0 * lda + (size_t)z * kspan;
  const bf16_t* Bb = Bt + (size_t)n0 * ldb + (size_t)z * kspan;
  int sr = lane & 15, sc = (lane >> 4) * 8;   // staging (row, col) within subtile

  f32x4_t acc[MF][4];
#pragma unroll
  for (int i = 0; i < MF; i++)
#pragma unroll
    for (int j = 0; j < 4; j++)
      acc[i][j] = (f32x4_t){0.f, 0.f, 0.f, 0.f};

  auto stage = [&](int buf, int kt) {
    int kg = kt * 64;
#pragma unroll
    for (int ch = 0; ch < ACH; ch++) {
      int sub = wave * ACH + ch;       // 0..31: frag_row = sub>>1, ks = sub&1
      gload16(Ab + (size_t)((sub >> 1) * 16 + sr) * lda + kg + (sub & 1) * 32 + sc,
              &As[buf][sub * 512]);
    }
#pragma unroll
    for (int ch = 0; ch < BCH; ch++) {
      int sub = wave * BCH + ch;
      gload16(Bb + (size_t)((sub >> 1) * 16 + sr) * ldb + kg + (sub & 1) * 32 + sc,
              &Bs[buf][sub * 512]);
    }
  };

  int nk = kspan / 64;
  stage(0, 0);
  stage(1, 1);
  int cur = 0;
  for (int kt = 0; kt < nk; ++kt) {
    // counted wait: stage(kt) landed; stage(kt+1)'s LPS loads stay in flight (T4)
    if (kt + 1 < nk) { asm volatile("s_waitcnt vmcnt(%0)" :: "n"(LPS) : "memory"); }
    else             { asm volatile("s_waitcnt vmcnt(0)" ::: "memory"); }
    __builtin_amdgcn_s_barrier();
#pragma unroll
    for (int ks = 0; ks < 2; ks++) {
      bf16x8_t af[MF], bfv[4];
#pragma unroll
      for (int i = 0; i < MF; i++)
        af[i] = *(const bf16x8_t*)(&As[cur][((wm * MF + i) * 2 + ks) * 512 + lane * 8]);
#pragma unroll
      for (int j = 0; j < 4; j++)
        bfv[j] = *(const bf16x8_t*)(&Bs[cur][((wn * 4 + j) * 2 + ks) * 512 + lane * 8]);
      __builtin_amdgcn_s_setprio(1);
#pragma unroll
      for (int i = 0; i < MF; i++)
#pragma unroll
        for (int j = 0; j < 4; j++)
          acc[i][j] = __builtin_amdgcn_mfma_f32_16x16x32_bf16(af[i], bfv[j], acc[i][j], 0, 0, 0);
      __builtin_amdgcn_s_setprio(0);
    }
    __builtin_amdgcn_sched_barrier(0);
    __builtin_amdgcn_s_barrier();      // all waves done reading buf cur
    if (kt + 2 < nk) stage(cur, kt + 2);
    cur ^= 1;
  }

  // epilogue: C/D frag layout col=lane&15, row=(lane>>4)*4+r
#pragma unroll
  for (int i = 0; i < MF; i++)
#pragma unroll
    for (int j = 0; j < 4; j++) {
      f32x4_t v = acc[i][j];
      int n = n0 + wn * 64 + j * 16 + (lane & 15);
      int mb = m0 + wm * (256 / WM) + i * 16 + (lane >> 4) * 4;
#pragma unroll
      for (int r = 0; r < 4; r++) {
        int m = mb + r;
        float val = v[r];
        if (bias) val += bias[n];
        if (relu) val = fmaxf(val, 0.f);
        if (MODE == MODE_F32) {
          size_t idx = (size_t)z * sCz + (size_t)m * N + n;
          ((float*)C)[idx] = val + (resid ? resid[idx] : 0.f);
        } else if (MODE == MODE_BF16) {
          size_t idx = (size_t)m * N + n;
          ((bf16_t*)C)[idx] = f2b(val);
        } else { // MODE_QKV: n in [0,3072): sect 0->q [B,H,T,D], 1->k [B,H,T,D], 2->v [B,H,D,T]
          int sect = n >> 10, hd = n & 1023, h = hd >> 6, d = hd & 63;
          int b = m >> 10, t = m & 1023;
          size_t base = (size_t)sect * ((size_t)B_ * H_ * T_ * D_);
          size_t idx = base + ((size_t)(b * H_ + h) << 16) +
                       (sect == 2 ? (size_t)((d << 10) + t) : (size_t)((t << 6) + d));
          ((bf16_t*)C)[idx] = f2b(val);
        }
      }
    }
}

// ---------------- split-K reduce: x = x + sum(partials) + bias ----------------
template <int NS>
__global__ __launch_bounds__(256) void splitk_reduce_kernel(const float* __restrict__ p,
                                                            float* __restrict__ x,
                                                            const float* __restrict__ bias) {
  size_t i = (size_t)blockIdx.x * 256 + threadIdx.x;   // float4 index
  float4 acc = ((float4*)x)[i];
  int n4 = (int)(i & (E_ / 4 - 1));
  float4 bv = ((const float4*)bias)[n4];
  acc.x += bv.x; acc.y += bv.y; acc.z += bv.z; acc.w += bv.w;
#pragma unroll
  for (int s = 0; s < NS; s++) {
    float4 a = ((const float4*)p)[i + (size_t)s * ((size_t)MTOK * E_ / 4)];
    acc.x += a.x; acc.y += a.y; acc.z += a.z; acc.w += a.w;
  }
  ((float4*)x)[i] = acc;
}

// ---------------- flash attention: per (bh, q-tile of 64); online softmax ----------------
// q,kk: [B,H,T,D]; vt: [B,H,D,T]; o: [B,T,H*D] bf16
#define KPAD 72

__global__ __launch_bounds__(256) void flash_kernel(
    const bf16_t* __restrict__ q,
    const bf16_t* __restrict__ kk,
    const bf16_t* __restrict__ vt,
    bf16_t* __restrict__ o) {
  __shared__ __align__(16) bf16_t Ks[64 * KPAD];
  __shared__ __align__(16) bf16_t Vs[64 * KPAD];     // Vt tile: [d][kv]
  __shared__ __align__(16) bf16_t Ps[4][16 * KPAD];
  int bid = blockIdx.x;
  int qi = 15 - (bid >> 6);          // heavy tiles dispatched first
  int bh = bid & 63;
  int b = bh >> 4, h = bh & 15;
  const bf16_t* qb = q + ((size_t)bh << 16);   // T*D = 65536
  const bf16_t* kb = kk + ((size_t)bh << 16);
  const bf16_t* vb = vt + ((size_t)bh << 16);
  int tid = threadIdx.x, lane = tid & 63, wave = tid >> 6;
  int lr = lane & 15, lg = lane >> 4;          // lg in 0..3
  int qbase = qi * 64;

  bf16x8_t qf[2];
  {
    const bf16_t* qrow = qb + (size_t)(qbase + wave * 16 + lr) * D_ + lg * 8;
    qf[0] = *(const bf16x8_t*)(qrow);
    qf[1] = *(const bf16x8_t*)(qrow + 32);
  }

  float m_r[4], l_r[4];
  f32x4_t oc[4];
#pragma unroll
  for (int r = 0; r < 4; r++) { m_r[r] = -1e30f; l_r[r] = 0.f; }
#pragma unroll
  for (int j = 0; j < 4; j++) oc[j] = (f32x4_t){0.f, 0.f, 0.f, 0.f};

  int srow = tid >> 2, scol = (tid & 3) * 16;

  // preload s=0 K/V into regs (T14: issue early, write late)
  bf16x8_t k0, k1, v0, v1;
  {
    const bf16_t* kg = kb + (size_t)srow * D_ + scol;
    k0 = *(const bf16x8_t*)kg;
    k1 = *(const bf16x8_t*)(kg + 8);
    const bf16_t* vg = vb + (size_t)srow * T_ + scol;
    v0 = *(const bf16x8_t*)vg;
    v1 = *(const bf16x8_t*)(vg + 8);
  }

  for (int s = 0; s <= qi; s++) {
    __syncthreads();
    *(bf16x8_t*)(&Ks[srow * KPAD + scol]) = k0;
    *(bf16x8_t*)(&Ks[srow * KPAD + scol + 8]) = k1;
    *(bf16x8_t*)(&Vs[srow * KPAD + scol]) = v0;
    *(bf16x8_t*)(&Vs[srow * KPAD + scol + 8]) = v1;
    __syncthreads();

    if (s < qi) {
      int kv1 = (s + 1) * 64;
      const bf16_t* kg = kb + (size_t)(kv1 + srow) * D_ + scol;
      k0 = *(const bf16x8_t*)kg;
      k1 = *(const bf16x8_t*)(kg + 8);
      const bf16_t* vg = vb + (size_t)srow * T_ + kv1 + scol;
      v0 = *(const bf16x8_t*)vg;
      v1 = *(const bf16x8_t*)(vg + 8);
    }

    int kv0 = s * 64;
    f32x4_t sc[4];
#pragma unroll
    for (int j = 0; j < 4; j++) {
      f32x4_t a = (f32x4_t){0.f, 0.f, 0.f, 0.f};
      bf16x8_t b0 = *(const bf16x8_t*)(&Ks[(j * 16 + lr) * KPAD + lg * 8]);
      bf16x8_t b1 = *(const bf16x8_t*)(&Ks[(j * 16 + lr) * KPAD + lg * 8 + 32]);
      a = __builtin_amdgcn_mfma_f32_16x16x32_bf16(qf[0], b0, a, 0, 0, 0);
      a = __builtin_amdgcn_mfma_f32_16x16x32_bf16(qf[1], b1, a, 0, 0, 0);
      sc[j] = a;
    }
    if (s == qi) {
#pragma unroll
      for (int j = 0; j < 4; j++)
#pragma unroll
        for (int r = 0; r < 4; r++) {
          int kvp = kv0 + j * 16 + lr;
          int qp  = qbase + wave * 16 + lg * 4 + r;
          sc[j][r] = (kvp <= qp) ? sc[j][r] * 0.125f : -1e30f;
        }
    } else {
#pragma unroll
      for (int j = 0; j < 4; j++)
#pragma unroll
        for (int r = 0; r < 4; r++) sc[j][r] *= 0.125f;
    }

    float ex[4];
#pragma unroll
    for (int r = 0; r < 4; r++) {
      float v = fmaxf(fmaxf(sc[0][r], sc[1][r]), fmaxf(sc[2][r], sc[3][r]));
      v = fmaxf(v, __shfl_xor(v, 1, 64));
      v = fmaxf(v, __shfl_xor(v, 2, 64));
      v = fmaxf(v, __shfl_xor(v, 4, 64));
      v = fmaxf(v, __shfl_xor(v, 8, 64));
      float mn = fmaxf(m_r[r], v);
      ex[r] = __expf(m_r[r] - mn);
      m_r[r] = mn;
      l_r[r] *= ex[r];
    }
#pragma unroll
    for (int j = 0; j < 4; j++)
#pragma unroll
      for (int r = 0; r < 4; r++) {
        float p = __expf(sc[j][r] - m_r[r]);
        l_r[r] += p;
        Ps[wave][(lg * 4 + r) * KPAD + j * 16 + lr] = f2b(p);
      }

#pragma unroll
    for (int j = 0; j < 4; j++)
#pragma unroll
      for (int r = 0; r < 4; r++) oc[j][r] *= ex[r];

    bf16x8_t pa0 = *(const bf16x8_t*)(&Ps[wave][lr * KPAD + lg * 8]);
    bf16x8_t pa1 = *(const bf16x8_t*)(&Ps[wave][lr * KPAD + lg * 8 + 32]);
#pragma unroll
    for (int j = 0; j < 4; j++) {
      bf16x8_t vb0 = *(const bf16x8_t*)(&Vs[(j * 16 + lr) * KPAD + lg * 8]);
      bf16x8_t vb1 = *(const bf16x8_t*)(&Vs[(j * 16 + lr) * KPAD + lg * 8 + 32]);
      oc[j] = __builtin_amdgcn_mfma_f32_16x16x32_bf16(pa0, vb0, oc[j], 0, 0, 0);
      oc[j] = __builtin_amdgcn_mfma_f32_16x16x32_bf16(pa1, vb1, oc[j], 0, 0, 0);
    }
  }

#pragma unroll
  for (int r = 0; r < 4; r++) {
    float v = l_r[r];
    v += __shfl_xor(v, 1, 64);
    v += __shfl_xor(v, 2, 64);
    v += __shfl_xor(v, 4, 64);
    v += __shfl_xor(v, 8, 64);
    l_r[r] = 1.f / v;
  }
  bf16_t* ob = o + ((size_t)(b * T_ + qbase + wave * 16)) * (H_ * D_) + h * D_;
#pragma unroll
  for (int j = 0; j < 4; j++)
#pragma unroll
    for (int r = 0; r < 4; r++) {
      int qrow = lg * 4 + r;
      ob[(size_t)qrow * (H_ * D_) + j * 16 + lr] = f2b(oc[j][r] * l_r[r]);
    }
}

// ---------------- host launch ----------------
extern "C" void kernel_launch(void* const* d_in, const int* in_sizes, int n_in,
                              void* d_out, int out_size, void* d_ws, size_t ws_size,
                              hipStream_t stream) {
  (void)in_sizes; (void)n_in; (void)out_size; (void)ws_size;
  const int*   tokens = (const int*)d_in[0];
  const float* tok_emb = (const float*)d_in[1];
  const float* pos_emb = (const float*)d_in[2];
  const float* Wq = (const float*)d_in[3];
  const float* Wk = (const float*)d_in[4];
  const float* Wv = (const float*)d_in[5];
  const float* Wo = (const float*)d_in[6];
  const float* bo = (const float*)d_in[7];
  const float* ln1_g = (const float*)d_in[8];
  const float* ln1_b = (const float*)d_in[9];
  const float* ln2_g = (const float*)d_in[10];
  const float* ln2_b = (const float*)d_in[11];
  const float* W1 = (const float*)d_in[12];
  const float* b1 = (const float*)d_in[13];
  const float* W2 = (const float*)d_in[14];
  const float* b2 = (const float*)d_in[15];
  const float* lnf_g = (const float*)d_in[16];
  const float* lnf_b = (const float*)d_in[17];
  const float* Wlm = (const float*)d_in[18];
  const float* blm = (const float*)d_in[19];

  char* w = (char*)d_ws;
  size_t off = 0;
  auto alloc = [&](size_t bytes) { void* p = (void*)(w + off); off += (bytes + 255) & ~(size_t)255; return p; };
  float*  x    = (float*)alloc((size_t)MTOK * E_ * 4);
  bf16_t* xb   = (bf16_t*)alloc((size_t)MTOK * E_ * 2);
  bf16_t* q    = (bf16_t*)alloc((size_t)B_ * H_ * T_ * D_ * 2);  // q,kk,vt contiguous (QKV epilogue)
  bf16_t* kk   = (bf16_t*)alloc((size_t)B_ * H_ * T_ * D_ * 2);
  bf16_t* vt   = (bf16_t*)alloc((size_t)B_ * H_ * T_ * D_ * 2);  // [B,H,D,T]
  bf16_t* o    = (bf16_t*)alloc((size_t)MTOK * E_ * 2);
  bf16_t* h1   = (bf16_t*)alloc((size_t)MTOK * FF_ * 2);
  bf16_t* WqkvT = (bf16_t*)alloc((size_t)3 * E_ * H_ * D_ * 2);
  bf16_t* WoT  = (bf16_t*)alloc((size_t)E_ * H_ * D_ * 2);
  bf16_t* W1T  = (bf16_t*)alloc((size_t)E_ * FF_ * 2);
  bf16_t* W2T  = (bf16_t*)alloc((size_t)E_ * FF_ * 2);
  bf16_t* WlmT = (bf16_t*)alloc((size_t)E_ * V_ * 2);
  float*  p2   = (float*)alloc((size_t)2 * MTOK * E_ * 4);   // W2 split-K partials

  embed_kernel<<<MTOK, 256, 0, stream>>>(tokens, tok_emb, pos_emb, x);
  transpose_kernel<<<dim3(V_ / 32, E_ / 32, 1), dim3(32, 8), 0, stream>>>(Wlm, WlmT, E_, V_);

  for (int l = 0; l < LAYERS; l++) {
    ln_kernel<<<MTOK, 256, 0, stream>>>(x, xb, ln1_g + l * E_, ln1_b + l * E_);

    // fused QKV weight transpose -> WqkvT [3*1024][1024], section-major
    transpose_kernel<<<dim3(D_ / 32, E_ / 32, H_), dim3(32, 8), 0, stream>>>(
        Wq + (size_t)l * H_ * E_ * D_, WqkvT, E_, D_);
    transpose_kernel<<<dim3(D_ / 32, E_ / 32, H_), dim3(32, 8), 0, stream>>>(
        Wk + (size_t)l * H_ * E_ * D_, WqkvT + (size_t)E_ * H_ * D_, E_, D_);
    transpose_kernel<<<dim3(D_ / 32, E_ / 32, H_), dim3(32, 8), 0, stream>>>(
        Wv + (size_t)l * H_ * E_ * D_, WqkvT + (size_t)2 * E_ * H_ * D_, E_, D_);
    transpose_kernel<<<dim3(E_ / 32, (H_ * D_) / 32, 1), dim3(32, 8), 0, stream>>>(
        Wo + (size_t)l * H_ * D_ * E_, WoT, H_ * D_, E_);
    transpose_kernel<<<dim3(FF_ / 32, E_ / 32, 1), dim3(32, 8), 0, stream>>>(
        W1 + (size_t)l * E_ * FF_, W1T, E_, FF_);
    transpose_kernel<<<dim3(E_ / 32, FF_ / 32, 1), dim3(32, 8), 0, stream>>>(
        W2 + (size_t)l * FF_ * E_, W2T, FF_, E_);

    // fused QKV projection: [MTOK,E] x [3072,E]^T, scatter epilogue
    gemm256_kernel<256, MODE_QKV><<<dim3(12, 16, 1), 512, 0, stream>>>(
        xb, E_, WqkvT, E_, q, 0, nullptr, nullptr, MTOK, 3 * H_ * D_, E_, 0);

    // flash attention
    flash_kernel<<<1024, 256, 0, stream>>>(q, kk, vt, o);

    // output projection + residual (residual = post-LN1 x, per reference)
    gemm256_kernel<128, MODE_F32><<<dim3(8, 16, 1), 512, 0, stream>>>(
        o, H_ * D_, WoT, H_ * D_, x, 0, bo + l * E_, x, MTOK, E_, H_ * D_, 0);

    ln_kernel<<<MTOK, 256, 0, stream>>>(x, xb, ln2_g + l * E_, ln2_b + l * E_);

    // FFN
    gemm256_kernel<256, MODE_BF16><<<dim3(16, 16, 1), 512, 0, stream>>>(
        xb, E_, W1T, E_, h1, 0, b1 + l * FF_, nullptr, MTOK, FF_, E_, 1);
    gemm256_kernel<128, MODE_F32><<<dim3(8, 16, 2), 512, 0, stream>>>(
        h1, FF_, W2T, FF_, p2, (long long)MTOK * E_, nullptr, nullptr, MTOK, E_, FF_ / 2, 0);
    splitk_reduce_kernel<2><<<MTOK * E_ / 1024, 256, 0, stream>>>(p2, x, b2 + l * E_);
  }

  ln_kernel<<<MTOK, 256, 0, stream>>>(x, xb, lnf_g, lnf_b);
  gemm256_kernel<128, MODE_F32><<<dim3(16, 16, 1), 512, 0, stream>>>(
      xb, E_, WlmT, E_, d_out, 0, blm, nullptr, MTOK, V_, E_, 0);
}

// Round 7
// 2232.662 us; speedup vs baseline: 1.2941x; 1.2941x over previous
//
#include <hip/hip_runtime.h>
#include <hip/hip_bf16.h>

#define LAYERS 8
#define H_ 16
#define E_ 1024
#define D_ 64
#define FF_ 4096
#define V_ 2048
#define B_ 4
#define T_ 1024
#define MTOK (B_*T_)

typedef __bf16 bf16x8_t __attribute__((ext_vector_type(8)));
typedef __bf16 bf16x4_t __attribute__((ext_vector_type(4)));
typedef float f32x4_t __attribute__((ext_vector_type(4)));
typedef __hip_bfloat16 bf16_t;

__device__ __forceinline__ bf16_t f2b(float f) { return __float2bfloat16(f); }

// ---------------- embedding: x = bf16(tok_emb[tok] + pos_emb[tok]) (pos indexed by TOKEN id) ----
__global__ void embed_kernel(const int* __restrict__ tokens,
                             const float* __restrict__ te,
                             const float* __restrict__ pe,
                             bf16_t* __restrict__ x) {
  int row = blockIdx.x;
  int tok = tokens[row];
  int t = threadIdx.x;
  float4 va = ((const float4*)(te + (size_t)tok * E_))[t];
  float4 vp = ((const float4*)(pe + (size_t)tok * E_))[t];
  bf16x4_t o;
  o[0] = (__bf16)(va.x + vp.x); o[1] = (__bf16)(va.y + vp.y);
  o[2] = (__bf16)(va.z + vp.z); o[3] = (__bf16)(va.w + vp.w);
  ((bf16x4_t*)(x + (size_t)row * E_))[t] = o;
}

// ---------------- layernorm: xout = bf16(ln(xin)); bf16 in/out, f32 stats ----------------
__global__ __launch_bounds__(256) void ln_kernel(const bf16_t* __restrict__ xin,
                                                 bf16_t* __restrict__ xout,
                                                 const float* __restrict__ g,
                                                 const float* __restrict__ b) {
  int row = blockIdx.x, tid = threadIdx.x;
  bf16x4_t v4 = ((const bf16x4_t*)(xin + (size_t)row * E_))[tid];
  float v0 = (float)v4[0], v1 = (float)v4[1], v2 = (float)v4[2], v3 = (float)v4[3];
  float s  = v0 + v1 + v2 + v3;
  float sq = v0*v0 + v1*v1 + v2*v2 + v3*v3;
  for (int off = 32; off; off >>= 1) {
    s  += __shfl_xor(s, off, 64);
    sq += __shfl_xor(sq, off, 64);
  }
  __shared__ float2 wred[4];
  if ((tid & 63) == 0) wred[tid >> 6] = make_float2(s, sq);
  __syncthreads();
  float2 w0 = wred[0], w1 = wred[1], w2 = wred[2], w3 = wred[3];
  float S = w0.x + w1.x + w2.x + w3.x, SQ = w0.y + w1.y + w2.y + w3.y;
  float mean = S * (1.0f / E_);
  float var  = SQ * (1.0f / E_) - mean * mean;
  float inv = rsqrtf(var + 1e-5f);
  float4 gv = ((const float4*)g)[tid];
  float4 bv = ((const float4*)b)[tid];
  bf16x4_t o;
  o[0] = (__bf16)((v0 - mean) * inv * gv.x + bv.x);
  o[1] = (__bf16)((v1 - mean) * inv * gv.y + bv.y);
  o[2] = (__bf16)((v2 - mean) * inv * gv.z + bv.z);
  o[3] = (__bf16)((v3 - mean) * inv * gv.w + bv.w);
  ((bf16x4_t*)(xout + (size_t)row * E_))[tid] = o;
}

// ---------------- batched transpose + fp32->bf16: out[z][c][r] = in[z][r][c] ----------------
__global__ void transpose_kernel(const float* __restrict__ in, bf16_t* __restrict__ out,
                                 int R, int C) {
  __shared__ float tile[32][33];
  int z = blockIdx.z;
  const float* ib = in + (size_t)z * R * C;
  bf16_t* ob = out + (size_t)z * R * C;
  int r0 = blockIdx.y * 32, c0 = blockIdx.x * 32;
  int tx = threadIdx.x, ty = threadIdx.y;   // (32,8)
  for (int i = 0; i < 4; i++)
    tile[ty + i * 8][tx] = ib[(size_t)(r0 + ty + i * 8) * C + (c0 + tx)];
  __syncthreads();
  for (int i = 0; i < 4; i++)
    ob[(size_t)(c0 + ty + i * 8) * R + (r0 + tx)] = f2b(tile[tx][ty + i * 8]);
}

// ---------------- m97-style MFMA GEMM, double-buffered LDS + 1-deep prefetch ----------------
// A: [M,K] bf16 rows stride lda; Bt: [N,K] bf16 rows stride ldb. Dims exact tile multiples.
#define BK 32

enum { MODE_F32 = 0, MODE_BF16 = 1, MODE_QKV = 2, MODE_BF16R = 3 };

__device__ __forceinline__ void gload16(const bf16_t* g, bf16_t* l) {
  __builtin_amdgcn_global_load_lds((const __attribute__((address_space(1))) void*)g,
                                   (__attribute__((address_space(3))) void*)l, 16, 0, 0);
}

// bijective XCD-aware swizzle (m204): contiguous tile chunk per XCD
__device__ __forceinline__ int xcd_swz(int flat, int nwg) {
  int q = nwg >> 3, r = nwg & 7;
  int xcd = flat & 7, idx = flat >> 3;
  return (xcd < r ? xcd * (q + 1) : r * (q + 1) + (xcd - r) * q) + idx;
}

template <int BM, int BN, int MODE>
__global__ __launch_bounds__(256) void gemm97_kernel(
    const bf16_t* __restrict__ A, long long sAz, int lda,
    const bf16_t* __restrict__ Bt, long long sBz, int ldb,
    void* __restrict__ C, long long sCz,
    const float* __restrict__ bias,
    const void* __restrict__ resid,
    int M, int N, int K, int relu) {
  constexpr int FR = BM / 32, FC = BN / 32;     // per-wave 16x16 frags (waves 2x2)
  constexpr int A_ISS = BM / 64, B_ISS = BN / 64;
  __shared__ __align__(16) bf16_t As[2][BM * BK];
  __shared__ __align__(16) bf16_t Bs[2][BN * BK];
  int tid = threadIdx.x;
  int z = blockIdx.z;
  int nwg = gridDim.x * gridDim.y;
  int flat = xcd_swz(blockIdx.y * gridDim.x + blockIdx.x, nwg);
  int m0 = (flat / gridDim.x) * BM, n0 = (flat % gridDim.x) * BN;
  const bf16_t* Ab = A + (size_t)z * sAz + (size_t)m0 * lda;
  const bf16_t* Bb = Bt + (size_t)z * sBz + (size_t)n0 * ldb;
  int lane = tid & 63, wave = tid >> 6;
  int wr = (wave >> 1) * (BM / 2), wc = (wave & 1) * (BN / 2);
  int lr = lane & 15, lk = (lane >> 4) * 8;
  int srow = tid >> 2;            // 0..63
  int scol = (tid & 3) * 8;       // 0,8,16,24

  f32x4_t acc[FR][FC];
  for (int i = 0; i < FR; i++)
    for (int j = 0; j < FC; j++)
      acc[i][j] = (f32x4_t){0.f, 0.f, 0.f, 0.f};

  auto stage = [&](int buf, int k0) {
#pragma unroll
    for (int i = 0; i < A_ISS; i++)
      gload16(Ab + (size_t)(i * 64 + srow) * lda + k0 + scol, &As[buf][i * 2048 + wave * 512]);
#pragma unroll
    for (int i = 0; i < B_ISS; i++)
      gload16(Bb + (size_t)(i * 64 + srow) * ldb + k0 + scol, &Bs[buf][i * 2048 + wave * 512]);
  };

  int nk = K / BK;
  stage(0, 0);
  __syncthreads();
  int cur = 0;
  for (int kt = 0; kt < nk; ++kt) {
    if (kt + 1 < nk) stage(cur ^ 1, (kt + 1) * BK);   // prefetch next tile
    bf16x8_t af[FR], bfv[FC];
#pragma unroll
    for (int i = 0; i < FR; i++)
      af[i] = *(const bf16x8_t*)(&As[cur][(wr + i * 16 + lr) * BK + lk]);
#pragma unroll
    for (int j = 0; j < FC; j++)
      bfv[j] = *(const bf16x8_t*)(&Bs[cur][(wc + j * 16 + lr) * BK + lk]);
#pragma unroll
    for (int i = 0; i < FR; i++)
#pragma unroll
      for (int j = 0; j < FC; j++)
        acc[i][j] = __builtin_amdgcn_mfma_f32_16x16x32_bf16(af[i], bfv[j], acc[i][j], 0, 0, 0);
    __syncthreads();
    cur ^= 1;
  }

  // epilogue: C/D frag layout col=lane&15, row=(lane>>4)*4+r
#pragma unroll
  for (int i = 0; i < FR; i++)
#pragma unroll
    for (int j = 0; j < FC; j++) {
      f32x4_t v = acc[i][j];
      int n = n0 + wc + j * 16 + lr;
      int mb = m0 + wr + i * 16 + (lane >> 4) * 4;
#pragma unroll
      for (int r = 0; r < 4; r++) {
        int m = mb + r;
        float val = v[r];
        if (bias) val += bias[n];
        if (relu) val = fmaxf(val, 0.f);
        if (MODE == MODE_F32) {
          size_t idx = (size_t)z * sCz + (size_t)m * N + n;
          ((float*)C)[idx] = val + (resid ? ((const float*)resid)[idx] : 0.f);
        } else if (MODE == MODE_BF16) {
          size_t idx = (size_t)z * sCz + (size_t)m * N + n;
          ((bf16_t*)C)[idx] = f2b(val);
        } else if (MODE == MODE_BF16R) {
          size_t idx = (size_t)m * N + n;
          val += __bfloat162float(((const bf16_t*)resid)[idx]);
          ((bf16_t*)C)[idx] = f2b(val);
        } else { // MODE_QKV: n in [0,3072): sect 0->q [B,H,T,D], 1->k [B,H,T,D], 2->v [B,H,D,T]
          int sect = n >> 10, hd = n & 1023, h = hd >> 6, d = hd & 63;
          int b = m >> 10, t = m & 1023;
          size_t base = (size_t)sect * ((size_t)B_ * H_ * T_ * D_);
          size_t idx = base + ((size_t)(b * H_ + h) << 16) +
                       (sect == 2 ? (size_t)((d << 10) + t) : (size_t)((t << 6) + d));
          ((bf16_t*)C)[idx] = f2b(val);
        }
      }
    }
}

// ---------------- split-K reduce (bf16): r = t + sum(partials) + bias ----------------
template <int NS>
__global__ __launch_bounds__(256) void splitk_reduce_kernel(const bf16_t* __restrict__ p,
                                                            const bf16_t* __restrict__ t,
                                                            bf16_t* __restrict__ r,
                                                            const float* __restrict__ bias) {
  size_t i = (size_t)blockIdx.x * 256 + threadIdx.x;   // bf16x8 index
  bf16x8_t tv = ((const bf16x8_t*)t)[i];
  int base = (int)((i * 8) & (E_ - 1));
  float acc[8];
#pragma unroll
  for (int j = 0; j < 8; j++) acc[j] = (float)tv[j] + bias[base + j];
#pragma unroll
  for (int s = 0; s < NS; s++) {
    bf16x8_t pv = ((const bf16x8_t*)p)[i + (size_t)s * ((size_t)MTOK * E_ / 8)];
#pragma unroll
    for (int j = 0; j < 8; j++) acc[j] += (float)pv[j];
  }
  bf16x8_t ov;
#pragma unroll
  for (int j = 0; j < 8; j++) ov[j] = (__bf16)acc[j];
  ((bf16x8_t*)r)[i] = ov;
}

// ---------------- flash attention: per (bh, q-tile of 64); online softmax ----------------
// q,kk: [B,H,T,D]; vt: [B,H,D,T]; o: [B,T,H*D] bf16
#define KPAD 72

__global__ __launch_bounds__(256) void flash_kernel(
    const bf16_t* __restrict__ q,
    const bf16_t* __restrict__ kk,
    const bf16_t* __restrict__ vt,
    bf16_t* __restrict__ o) {
  __shared__ __align__(16) bf16_t Ks[64 * KPAD];
  __shared__ __align__(16) bf16_t Vs[64 * KPAD];     // Vt tile: [d][kv]
  __shared__ __align__(16) bf16_t Ps[4][16 * KPAD];
  int bid = blockIdx.x;
  int qi = 15 - (bid >> 6);          // heavy tiles dispatched first
  int bh = bid & 63;
  int b = bh >> 4, h = bh & 15;
  const bf16_t* qb = q + ((size_t)bh << 16);   // T*D = 65536
  const bf16_t* kb = kk + ((size_t)bh << 16);
  const bf16_t* vb = vt + ((size_t)bh << 16);
  int tid = threadIdx.x, lane = tid & 63, wave = tid >> 6;
  int lr = lane & 15, lg = lane >> 4;          // lg in 0..3
  int qbase = qi * 64;

  bf16x8_t qf[2];
  {
    const bf16_t* qrow = qb + (size_t)(qbase + wave * 16 + lr) * D_ + lg * 8;
    qf[0] = *(const bf16x8_t*)(qrow);
    qf[1] = *(const bf16x8_t*)(qrow + 32);
  }

  float m_r[4], l_r[4];
  f32x4_t oc[4];
#pragma unroll
  for (int r = 0; r < 4; r++) { m_r[r] = -1e30f; l_r[r] = 0.f; }
#pragma unroll
  for (int j = 0; j < 4; j++) oc[j] = (f32x4_t){0.f, 0.f, 0.f, 0.f};

  int srow = tid >> 2, scol = (tid & 3) * 16;

  // preload s=0 K/V into regs (T14: issue early, write late)
  bf16x8_t k0, k1, v0, v1;
  {
    const bf16_t* kg = kb + (size_t)srow * D_ + scol;
    k0 = *(const bf16x8_t*)kg;
    k1 = *(const bf16x8_t*)(kg + 8);
    const bf16_t* vg = vb + (size_t)srow * T_ + scol;
    v0 = *(const bf16x8_t*)vg;
    v1 = *(const bf16x8_t*)(vg + 8);
  }

  for (int s = 0; s <= qi; s++) {
    __syncthreads();
    *(bf16x8_t*)(&Ks[srow * KPAD + scol]) = k0;
    *(bf16x8_t*)(&Ks[srow * KPAD + scol + 8]) = k1;
    *(bf16x8_t*)(&Vs[srow * KPAD + scol]) = v0;
    *(bf16x8_t*)(&Vs[srow * KPAD + scol + 8]) = v1;
    __syncthreads();

    if (s < qi) {
      int kv1 = (s + 1) * 64;
      const bf16_t* kg = kb + (size_t)(kv1 + srow) * D_ + scol;
      k0 = *(const bf16x8_t*)kg;
      k1 = *(const bf16x8_t*)(kg + 8);
      const bf16_t* vg = vb + (size_t)srow * T_ + kv1 + scol;
      v0 = *(const bf16x8_t*)vg;
      v1 = *(const bf16x8_t*)(vg + 8);
    }

    int kv0 = s * 64;
    f32x4_t sc[4];
#pragma unroll
    for (int j = 0; j < 4; j++) {
      f32x4_t a = (f32x4_t){0.f, 0.f, 0.f, 0.f};
      bf16x8_t b0 = *(const bf16x8_t*)(&Ks[(j * 16 + lr) * KPAD + lg * 8]);
      bf16x8_t b1 = *(const bf16x8_t*)(&Ks[(j * 16 + lr) * KPAD + lg * 8 + 32]);
      a = __builtin_amdgcn_mfma_f32_16x16x32_bf16(qf[0], b0, a, 0, 0, 0);
      a = __builtin_amdgcn_mfma_f32_16x16x32_bf16(qf[1], b1, a, 0, 0, 0);
      sc[j] = a;
    }
    if (s == qi) {
#pragma unroll
      for (int j = 0; j < 4; j++)
#pragma unroll
        for (int r = 0; r < 4; r++) {
          int kvp = kv0 + j * 16 + lr;
          int qp  = qbase + wave * 16 + lg * 4 + r;
          sc[j][r] = (kvp <= qp) ? sc[j][r] * 0.125f : -1e30f;
        }
    } else {
#pragma unroll
      for (int j = 0; j < 4; j++)
#pragma unroll
        for (int r = 0; r < 4; r++) sc[j][r] *= 0.125f;
    }

    float ex[4];
#pragma unroll
    for (int r = 0; r < 4; r++) {
      float v = fmaxf(fmaxf(sc[0][r], sc[1][r]), fmaxf(sc[2][r], sc[3][r]));
      v = fmaxf(v, __shfl_xor(v, 1, 64));
      v = fmaxf(v, __shfl_xor(v, 2, 64));
      v = fmaxf(v, __shfl_xor(v, 4, 64));
      v = fmaxf(v, __shfl_xor(v, 8, 64));
      float mn = fmaxf(m_r[r], v);
      ex[r] = __expf(m_r[r] - mn);
      m_r[r] = mn;
      l_r[r] *= ex[r];
    }
#pragma unroll
    for (int j = 0; j < 4; j++)
#pragma unroll
      for (int r = 0; r < 4; r++) {
        float p = __expf(sc[j][r] - m_r[r]);
        l_r[r] += p;
        Ps[wave][(lg * 4 + r) * KPAD + j * 16 + lr] = f2b(p);
      }

#pragma unroll
    for (int j = 0; j < 4; j++)
#pragma unroll
      for (int r = 0; r < 4; r++) oc[j][r] *= ex[r];

    bf16x8_t pa0 = *(const bf16x8_t*)(&Ps[wave][lr * KPAD + lg * 8]);
    bf16x8_t pa1 = *(const bf16x8_t*)(&Ps[wave][lr * KPAD + lg * 8 + 32]);
#pragma unroll
    for (int j = 0; j < 4; j++) {
      bf16x8_t vb0 = *(const bf16x8_t*)(&Vs[(j * 16 + lr) * KPAD + lg * 8]);
      bf16x8_t vb1 = *(const bf16x8_t*)(&Vs[(j * 16 + lr) * KPAD + lg * 8 + 32]);
      oc[j] = __builtin_amdgcn_mfma_f32_16x16x32_bf16(pa0, vb0, oc[j], 0, 0, 0);
      oc[j] = __builtin_amdgcn_mfma_f32_16x16x32_bf16(pa1, vb1, oc[j], 0, 0, 0);
    }
  }

#pragma unroll
  for (int r = 0; r < 4; r++) {
    float v = l_r[r];
    v += __shfl_xor(v, 1, 64);
    v += __shfl_xor(v, 2, 64);
    v += __shfl_xor(v, 4, 64);
    v += __shfl_xor(v, 8, 64);
    l_r[r] = 1.f / v;
  }
  bf16_t* ob = o + ((size_t)(b * T_ + qbase + wave * 16)) * (H_ * D_) + h * D_;
#pragma unroll
  for (int j = 0; j < 4; j++)
#pragma unroll
    for (int r = 0; r < 4; r++) {
      int qrow = lg * 4 + r;
      ob[(size_t)qrow * (H_ * D_) + j * 16 + lr] = f2b(oc[j][r] * l_r[r]);
    }
}

// ---------------- host launch ----------------
extern "C" void kernel_launch(void* const* d_in, const int* in_sizes, int n_in,
                              void* d_out, int out_size, void* d_ws, size_t ws_size,
                              hipStream_t stream) {
  (void)in_sizes; (void)n_in; (void)out_size; (void)ws_size;
  const int*   tokens = (const int*)d_in[0];
  const float* tok_emb = (const float*)d_in[1];
  const float* pos_emb = (const float*)d_in[2];
  const float* Wq = (const float*)d_in[3];
  const float* Wk = (const float*)d_in[4];
  const float* Wv = (const float*)d_in[5];
  const float* Wo = (const float*)d_in[6];
  const float* bo = (const float*)d_in[7];
  const float* ln1_g = (const float*)d_in[8];
  const float* ln1_b = (const float*)d_in[9];
  const float* ln2_g = (const float*)d_in[10];
  const float* ln2_b = (const float*)d_in[11];
  const float* W1 = (const float*)d_in[12];
  const float* b1 = (const float*)d_in[13];
  const float* W2 = (const float*)d_in[14];
  const float* b2 = (const float*)d_in[15];
  const float* lnf_g = (const float*)d_in[16];
  const float* lnf_b = (const float*)d_in[17];
  const float* Wlm = (const float*)d_in[18];
  const float* blm = (const float*)d_in[19];

  char* w = (char*)d_ws;
  size_t off = 0;
  auto alloc = [&](size_t bytes) { void* p = (void*)(w + off); off += (bytes + 255) & ~(size_t)255; return p; };
  bf16_t* r    = (bf16_t*)alloc((size_t)MTOK * E_ * 2);   // residual carrier (bf16)
  bf16_t* t    = (bf16_t*)alloc((size_t)MTOK * E_ * 2);   // LN output (bf16)
  bf16_t* q    = (bf16_t*)alloc((size_t)B_ * H_ * T_ * D_ * 2);  // q,kk,vt contiguous (QKV epilogue)
  bf16_t* kk   = (bf16_t*)alloc((size_t)B_ * H_ * T_ * D_ * 2);
  bf16_t* vt   = (bf16_t*)alloc((size_t)B_ * H_ * T_ * D_ * 2);  // [B,H,D,T]
  bf16_t* o    = (bf16_t*)alloc((size_t)MTOK * E_ * 2);
  bf16_t* h1   = (bf16_t*)alloc((size_t)MTOK * FF_ * 2);
  bf16_t* WqkvT = (bf16_t*)alloc((size_t)3 * E_ * H_ * D_ * 2);
  bf16_t* WoT  = (bf16_t*)alloc((size_t)E_ * H_ * D_ * 2);
  bf16_t* W1T  = (bf16_t*)alloc((size_t)E_ * FF_ * 2);
  bf16_t* W2T  = (bf16_t*)alloc((size_t)E_ * FF_ * 2);
  bf16_t* WlmT = (bf16_t*)alloc((size_t)E_ * V_ * 2);
  bf16_t* p2   = (bf16_t*)alloc((size_t)2 * MTOK * E_ * 2);   // W2 split-K partials (bf16)

  embed_kernel<<<MTOK, 256, 0, stream>>>(tokens, tok_emb, pos_emb, r);
  transpose_kernel<<<dim3(V_ / 32, E_ / 32, 1), dim3(32, 8), 0, stream>>>(Wlm, WlmT, E_, V_);

  for (int l = 0; l < LAYERS; l++) {
    ln_kernel<<<MTOK, 256, 0, stream>>>(r, t, ln1_g + l * E_, ln1_b + l * E_);

    // fused QKV weight transpose -> WqkvT [3*1024][1024], section-major
    transpose_kernel<<<dim3(D_ / 32, E_ / 32, H_), dim3(32, 8), 0, stream>>>(
        Wq + (size_t)l * H_ * E_ * D_, WqkvT, E_, D_);
    transpose_kernel<<<dim3(D_ / 32, E_ / 32, H_), dim3(32, 8), 0, stream>>>(
        Wk + (size_t)l * H_ * E_ * D_, WqkvT + (size_t)E_ * H_ * D_, E_, D_);
    transpose_kernel<<<dim3(D_ / 32, E_ / 32, H_), dim3(32, 8), 0, stream>>>(
        Wv + (size_t)l * H_ * E_ * D_, WqkvT + (size_t)2 * E_ * H_ * D_, E_, D_);
    transpose_kernel<<<dim3(E_ / 32, (H_ * D_) / 32, 1), dim3(32, 8), 0, stream>>>(
        Wo + (size_t)l * H_ * D_ * E_, WoT, H_ * D_, E_);
    transpose_kernel<<<dim3(FF_ / 32, E_ / 32, 1), dim3(32, 8), 0, stream>>>(
        W1 + (size_t)l * E_ * FF_, W1T, E_, FF_);
    transpose_kernel<<<dim3(E_ / 32, FF_ / 32, 1), dim3(32, 8), 0, stream>>>(
        W2 + (size_t)l * FF_ * E_, W2T, FF_, E_);

    // fused QKV projection: [MTOK,E] x [3072,E]^T, scatter epilogue
    gemm97_kernel<128, 128, MODE_QKV><<<dim3(24, 32, 1), 256, 0, stream>>>(
        t, 0, E_, WqkvT, 0, E_, q, 0, nullptr, nullptr, MTOK, 3 * H_ * D_, E_, 0);

    // flash attention
    flash_kernel<<<1024, 256, 0, stream>>>(q, kk, vt, o);

    // output projection + residual (residual = post-LN1 t, per reference) -> r (bf16)
    gemm97_kernel<128, 128, MODE_BF16R><<<dim3(8, 32, 1), 256, 0, stream>>>(
        o, 0, H_ * D_, WoT, 0, H_ * D_, r, 0, bo + l * E_, t, MTOK, E_, H_ * D_, 0);

    ln_kernel<<<MTOK, 256, 0, stream>>>(r, t, ln2_g + l * E_, ln2_b + l * E_);

    // FFN
    gemm97_kernel<128, 128, MODE_BF16><<<dim3(32, 32, 1), 256, 0, stream>>>(
        t, 0, E_, W1T, 0, E_, h1, 0, b1 + l * FF_, nullptr, MTOK, FF_, E_, 1);
    gemm97_kernel<128, 128, MODE_BF16><<<dim3(8, 32, 2), 256, 0, stream>>>(
        h1, 2048, FF_, W2T, 2048, FF_, p2, (long long)MTOK * E_,
        nullptr, nullptr, MTOK, E_, FF_ / 2, 0);
    splitk_reduce_kernel<2><<<MTOK * E_ / 2048, 256, 0, stream>>>(p2, t, r, b2 + l * E_);
  }

  ln_kernel<<<MTOK, 256, 0, stream>>>(r, t, lnf_g, lnf_b);
  gemm97_kernel<128, 128, MODE_F32><<<dim3(16, 32, 1), 256, 0, stream>>>(
      t, 0, E_, WlmT, 0, E_, d_out, 0, blm, nullptr, MTOK, V_, E_, 0);
}